// Round 1
// baseline (434.959 us; speedup 1.0000x reference)
//
#include <hip/hip_runtime.h>

#define N_NODES 50000
#define N_EDGES 600000
#define N_GRAPHS 2048
#define EMB 128
#define TDIM 384
#define TS_LD 392               // padded LDS row stride (shorts): 2-way bank alias only
#define HN (N_NODES * EMB)
#define SCAN_NB ((N_NODES + 255) / 256)   // 196

// merged-prepass block ranges (384 threads/block)
#define PRE_ATOM_NB 8334        // 6 nodes/block, FULL wave (64 lanes x float2) per node
#define PRE_HIST_NB 1563        // ceil(600000/384)
#define PRE_WCONV_NB 384        // one (layer,col) per block
#define PRE_GB_NB 131           // ceil(50000/384)

typedef __attribute__((ext_vector_type(8))) short bf16x8;
typedef __attribute__((ext_vector_type(4))) float f32x4;
#define MFMA_BF16(a, b, c) __builtin_amdgcn_mfma_f32_16x16x32_bf16(a, b, c, 0, 0, 0)

__device__ inline unsigned short f2bf(float f) {
  unsigned int u = __float_as_uint(f);
  u += 0x7fffu + ((u >> 16) & 1u);   // round to nearest even
  return (unsigned short)(u >> 16);
}
__device__ inline float bf2f(unsigned short b) {
  return __uint_as_float(((unsigned int)b) << 16);
}

// ---------------- merged prepass: atom-encoder | degree-hist | W-transpose | graph-bounds ----------
// Atom part: FULL wave per node. n is wave-uniform -> x-row reads are scalar loads.
// MLP fix vs prior round: all 9 gathers are issued into an explicit v[9] array BEFORE
// any accumulation, forcing 9 loads in flight (prior kernel: VGPR_Count=16 proved the
// compiler serialized them into a 9-deep latency chain -> 44 us at 11% HBM).
__global__ __launch_bounds__(384) void k_pre(const int* __restrict__ x,
                                             const float* __restrict__ atom_emb,
                                             unsigned short* __restrict__ h_bf,
                                             const int* __restrict__ ei,
                                             int* __restrict__ deg,
                                             const float* __restrict__ W,
                                             unsigned short* __restrict__ wt,
                                             const int* __restrict__ batch,
                                             int* __restrict__ gs) {
  int blk = blockIdx.x;
  if (blk < PRE_ATOM_NB) {
    int n = blk * 6 + (threadIdx.x >> 6);
    int lane = threadIdx.x & 63;    // covers cols lane*2, lane*2+1
    if (n < N_NODES) {
      const int nu = __builtin_amdgcn_readfirstlane(n);
      const int* xr = x + nu * 9;
      int ix[9];
#pragma unroll
      for (int c = 0; c < 9; ++c) ix[c] = xr[c];            // scalar loads, issued together
      float2 v[9];
#pragma unroll
      for (int c = 0; c < 9; ++c)                           // 9 gathers, all in flight
        v[c] = ((const float2*)(atom_emb + (size_t)(c * 100 + ix[c]) * EMB))[lane];
      float2 acc = {0.f, 0.f};
#pragma unroll
      for (int c = 0; c < 9; ++c) { acc.x += v[c].x; acc.y += v[c].y; }
      *(ushort2*)(h_bf + (size_t)nu * EMB + lane * 2) = ushort2{f2bf(acc.x), f2bf(acc.y)};
    }
    return;
  }
  blk -= PRE_ATOM_NB;
  if (blk < PRE_HIST_NB) {
    int e = blk * 384 + threadIdx.x;
    if (e < N_EDGES) atomicAdd(&deg[ei[N_EDGES + e]], 1);
    return;
  }
  blk -= PRE_HIST_NB;
  if (blk < PRE_WCONV_NB) {
    int layer = blk >> 7, c = blk & 127, k = threadIdx.x;
    float v = W[(((layer * 3 + (k >> 7)) * 128) + (k & 127)) * 128 + c];
    wt[(size_t)blk * 384 + k] = f2bf(v);
    return;
  }
  blk -= PRE_WCONV_NB;
  {
    int i = blk * 384 + threadIdx.x;
    if (i < N_NODES) {
      int b = batch[i];
      int bp = (i == 0) ? -1 : batch[i - 1];
      for (int g = bp + 1; g <= b; ++g) gs[g] = i;
      if (i == N_NODES - 1) {
        for (int g = b + 1; g <= N_GRAPHS; ++g) gs[g] = N_NODES;
      }
    }
  }
}

// ---------------- CSR scan ----------------
__global__ __launch_bounds__(256) void k_scan_a(const int* __restrict__ deg,
                                                int* __restrict__ row_start,
                                                int* __restrict__ partials) {
  __shared__ int s[256];
  const int tid = threadIdx.x;
  const int i = blockIdx.x * 256 + tid;
  int v = (i < N_NODES) ? deg[i] : 0;
  s[tid] = v;
  __syncthreads();
  for (int off = 1; off < 256; off <<= 1) {
    int t = (tid >= off) ? s[tid - off] : 0;
    __syncthreads();
    s[tid] += t;
    __syncthreads();
  }
  if (i < N_NODES) row_start[i] = s[tid] - v;
  if (tid == 255) partials[blockIdx.x] = s[255];
}

__global__ __launch_bounds__(256) void k_scan_b(int* __restrict__ partials,
                                                int* __restrict__ row_start) {
  __shared__ int s[256];
  const int tid = threadIdx.x;
  int v = (tid < SCAN_NB) ? partials[tid] : 0;
  s[tid] = v;
  __syncthreads();
  for (int off = 1; off < 256; off <<= 1) {
    int t = (tid >= off) ? s[tid - off] : 0;
    __syncthreads();
    s[tid] += t;
    __syncthreads();
  }
  if (tid < SCAN_NB) partials[tid] = s[tid] - v;
  if (tid == 255) row_start[N_NODES] = s[255];
}

__global__ __launch_bounds__(256) void k_scan_c(int* __restrict__ row_start,
                                                const int* __restrict__ partials,
                                                int* __restrict__ cursor) {
  const int i = blockIdx.x * 256 + threadIdx.x;
  if (i < N_NODES) {
    int r = row_start[i] + partials[blockIdx.x];
    row_start[i] = r;
    cursor[i] = r;
  }
}

// Scatter edges into CSR order: one int2{src, packed_attr} per edge.
__global__ __launch_bounds__(256) void k_scatter(const int* __restrict__ ei,
                                                 const int* __restrict__ ea,
                                                 int* __restrict__ cursor,
                                                 int2* __restrict__ sorted_se) {
  int e = blockIdx.x * 256 + threadIdx.x;
  if (e >= N_EDGES) return;
  int src = ei[e], dst = ei[N_EDGES + e];
  int pos = atomicAdd(&cursor[dst], 1);
  int eap = ea[e * 3 + 0] | (ea[e * 3 + 1] << 3) | (ea[e * 3 + 2] << 6);
  sorted_se[pos] = int2{src, eap};
}

// ---------------- FUSED edge-aggregation + MFMA GEMM (per layer) ----------------
// Removes the t_bf HBM round-trip (38.4 MB write + 38.4 MB read per layer): the 32-node
// aggregate tile is produced directly in LDS (identical f2bf rounding as the old t_bf
// path), then consumed by the per-wave MFMA GEMM.
// Block = 512 thr = 8 waves = 16 half-waves; 32 nodes/block; grid 1563.
// Agg: half-wave hw handles nodes {nb+hw, nb+16+hw}; lane sub covers cols sub*4..+3;
//      accumulators a0/a1/a2 are the 3 conv channels -> ts cols +0/+128/+256.
// GEMM: wave wv owns cols wv*16..+15: 12 resident B-frags, 2 row-tiles, 12 chained MFMAs.
// A-frag: A[m=lane&15][k=(lane>>4)*8+j]; B-frag: B[k][n=lane&15];
// C/D: col=lane&15, row=(lane>>4)*4+reg.  Epilogue: bias+relu + bf16 residual.
__global__ __launch_bounds__(512) void k_fused(const int2* __restrict__ sorted_se,
                                               const int* __restrict__ row_start,
                                               const float* __restrict__ bl,   // bond_emb[layer]: [3][8][3]
                                               const unsigned short* __restrict__ wt,  // [128][384]
                                               const float* __restrict__ bb,   // b[layer]: [3][128]
                                               const unsigned short* __restrict__ h_in_bf,
                                               unsigned short* __restrict__ h_out_bf,
                                               int do_relu) {
  __shared__ float4 combo[512];               // 8 KB bond-weight LUT
  __shared__ unsigned short ts[32 * TS_LD];   // 24.5 KB tile
  const int tid = threadIdx.x;

  {  // 512 threads, 512 LUT entries: one each
    int a0 = tid & 7, a1 = (tid >> 3) & 7, a2 = (tid >> 6) & 7;
    combo[tid] = float4{bl[a0 * 3 + 0] + bl[24 + a1 * 3 + 0] + bl[48 + a2 * 3 + 0],
                        bl[a0 * 3 + 1] + bl[24 + a1 * 3 + 1] + bl[48 + a2 * 3 + 1],
                        bl[a0 * 3 + 2] + bl[24 + a1 * 3 + 2] + bl[48 + a2 * 3 + 2], 0.f};
  }

  // GEMM-side constants (independent of agg; global loads overlap the agg phase)
  const int wv = tid >> 6;
  const int lane = tid & 63;
  const int m = lane & 15;
  const int kq = lane >> 4;
  const int c = wv * 16 + m;
  const unsigned short* pB = wt + (size_t)c * TDIM + kq * 8;
  bf16x8 B[12];
#pragma unroll
  for (int kc = 0; kc < 12; ++kc) B[kc] = *(const bf16x8*)(pB + kc * 32);
  const float bias = bb[c] + bb[128 + c] + bb[256 + c];

  __syncthreads();  // combo LUT ready

  // ---- aggregation phase: 16 half-waves x 2 nodes ----
  const int hw = tid >> 5;
  const int sub = tid & 31;                  // cols sub*4..+3
  const int nb = blockIdx.x * 32;
#pragma unroll
  for (int i = 0; i < 2; ++i) {
    const int node = nb + i * 16 + hw;
    float4 a0 = {0.f, 0.f, 0.f, 0.f}, a1 = a0, a2 = a0;
    if (node < N_NODES) {
      const int beg = row_start[node], end = row_start[node + 1];
      int e = beg;
      const int full_end = beg + ((end - beg) & ~7);
      for (; e < full_end; e += 8) {         // fast path: no bounds logic
        int2 se[8];
#pragma unroll
        for (int j = 0; j < 8; ++j) se[j] = sorted_se[e + j];
        ushort4 u[8];
#pragma unroll
        for (int j = 0; j < 8; ++j)
          u[j] = *(const ushort4*)(h_in_bf + (size_t)se[j].x * EMB + sub * 4);
#pragma unroll
        for (int j = 0; j < 8; ++j) {
          float4 w = combo[se[j].y];
          float4 vf = {bf2f(u[j].x), bf2f(u[j].y), bf2f(u[j].z), bf2f(u[j].w)};
          a0 += vf * w.x;
          a1 += vf * w.y;
          a2 += vf * w.z;
        }
      }
      if (e < end) {                         // tail chunk: clamped + weight-selected
        int2 se[8];
#pragma unroll
        for (int j = 0; j < 8; ++j) {
          int idx = e + j;
          se[j] = sorted_se[idx < end ? idx : end - 1];
        }
        ushort4 u[8];
#pragma unroll
        for (int j = 0; j < 8; ++j)
          u[j] = *(const ushort4*)(h_in_bf + (size_t)se[j].x * EMB + sub * 4);
#pragma unroll
        for (int j = 0; j < 8; ++j) {
          float4 w = (e + j < end) ? combo[se[j].y] : float4{0.f, 0.f, 0.f, 0.f};
          float4 vf = {bf2f(u[j].x), bf2f(u[j].y), bf2f(u[j].z), bf2f(u[j].w)};
          a0 += vf * w.x;
          a1 += vf * w.y;
          a2 += vf * w.z;
        }
      }
    }
    size_t base = (size_t)(i * 16 + hw) * TS_LD + sub * 4;
    *(ushort4*)(ts + base)       = ushort4{f2bf(a0.x), f2bf(a0.y), f2bf(a0.z), f2bf(a0.w)};
    *(ushort4*)(ts + base + 128) = ushort4{f2bf(a1.x), f2bf(a1.y), f2bf(a1.z), f2bf(a1.w)};
    *(ushort4*)(ts + base + 256) = ushort4{f2bf(a2.x), f2bf(a2.y), f2bf(a2.z), f2bf(a2.w)};
  }
  __syncthreads();  // tile ready

  // ---- GEMM phase ----
#pragma unroll
  for (int rt = 0; rt < 2; ++rt) {
    const unsigned short* pA = ts + (rt * 16 + m) * TS_LD + kq * 8;
    bf16x8 A[12];
#pragma unroll
    for (int kc = 0; kc < 12; ++kc) A[kc] = *(const bf16x8*)(pA + kc * 32);
    f32x4 acc = {0.f, 0.f, 0.f, 0.f};
#pragma unroll
    for (int kc = 0; kc < 12; ++kc) acc = MFMA_BF16(A[kc], B[kc], acc);
#pragma unroll
    for (int r = 0; r < 4; ++r) {
      int row = nb + rt * 16 + kq * 4 + r;
      if (row < N_NODES) {
        size_t idx = (size_t)row * EMB + c;
        float v = acc[r] + bias;
        if (do_relu) v = fmaxf(v, 0.f);
        float hn = bf2f(h_in_bf[idx]) + v;
        h_out_bf[idx] = f2bf(hn);
      }
    }
  }
}

// ---------------- fused mean-pool + head: block g reduces its contiguous node range ----------------
__global__ __launch_bounds__(128) void k_head(const unsigned short* __restrict__ h_bf,
                                              const int* __restrict__ gs,
                                              const float* __restrict__ fc1_w,
                                              const float* __restrict__ fc1_b,
                                              const float* __restrict__ fc2_w,
                                              const float* __restrict__ fc2_b,
                                              float* __restrict__ out) {
  __shared__ float hg[EMB];
  __shared__ float red[EMB];
  int g = blockIdx.x, e = threadIdx.x;
  int ns = gs[g], ne = gs[g + 1];
  float acc = 0.f;
  for (int n = ns; n < ne; ++n) acc += bf2f(h_bf[(size_t)n * EMB + e]);
  float cnt = fmaxf((float)(ne - ns), 1.f);
  hg[e] = acc / cnt;
  __syncthreads();
  float a2 = fc1_b[e];
  for (int j = 0; j < EMB; ++j) a2 += hg[j] * fc1_w[j * EMB + e];
  red[e] = a2 * fc2_w[e];
  __syncthreads();
  for (int s = 64; s > 0; s >>= 1) {
    if (e < s) red[e] += red[e + s];
    __syncthreads();
  }
  if (e == 0) out[g] = red[0] + fc2_b[0];
}

extern "C" void kernel_launch(void* const* d_in, const int* in_sizes, int n_in,
                              void* d_out, int out_size, void* d_ws, size_t ws_size,
                              hipStream_t stream) {
  const int*   x        = (const int*)d_in[0];
  const int*   ei       = (const int*)d_in[1];
  const int*   ea       = (const int*)d_in[2];
  const int*   batch    = (const int*)d_in[3];
  const float* atom_emb = (const float*)d_in[4];
  const float* bond_emb = (const float*)d_in[5];
  const float* W        = (const float*)d_in[6];
  const float* b        = (const float*)d_in[7];
  const float* fc1_w    = (const float*)d_in[8];
  const float* fc1_b    = (const float*)d_in[9];
  const float* fc2_w    = (const float*)d_in[10];
  const float* fc2_b    = (const float*)d_in[11];
  float* out = (float*)d_out;

  char* p = (char*)d_ws;
  auto alloc = [&](size_t bytes) { char* r = p; p += (bytes + 255) & ~(size_t)255; return r; };
  unsigned short* h0_bf      = (unsigned short*)alloc((size_t)HN * 2);
  unsigned short* h1_bf      = (unsigned short*)alloc((size_t)HN * 2);
  unsigned short* wt         = (unsigned short*)alloc((size_t)3 * 128 * TDIM * 2);
  int*            gs         = (int*)alloc((size_t)(N_GRAPHS + 1) * 4);
  int*            deg        = (int*)alloc((size_t)N_NODES * 4);
  int*            row_start  = (int*)alloc((size_t)(N_NODES + 1) * 4);
  int*            cursor     = (int*)alloc((size_t)N_NODES * 4);
  int*            partials   = (int*)alloc(256 * 4);
  int2*           sorted_se  = (int2*)alloc((size_t)(N_EDGES + 8) * 8);

  hipMemsetAsync(deg, 0, N_NODES * sizeof(int), stream);
  const int pre_blocks = PRE_ATOM_NB + PRE_HIST_NB + PRE_WCONV_NB + PRE_GB_NB;
  k_pre<<<pre_blocks, 384, 0, stream>>>(x, atom_emb, h0_bf, ei, deg, W, wt, batch, gs);
  k_scan_a<<<SCAN_NB, 256, 0, stream>>>(deg, row_start, partials);
  k_scan_b<<<1, 256, 0, stream>>>(partials, row_start);
  k_scan_c<<<SCAN_NB, 256, 0, stream>>>(row_start, partials, cursor);
  k_scatter<<<(N_EDGES + 255) / 256, 256, 0, stream>>>(ei, ea, cursor, sorted_se);

  unsigned short* hib = h0_bf;
  unsigned short* hob = h1_bf;
  const int fused_blocks = (N_NODES + 31) / 32;  // 1563
  for (int layer = 0; layer < 3; ++layer) {
    k_fused<<<fused_blocks, 512, 0, stream>>>(
        sorted_se, row_start, bond_emb + layer * 72,
        wt + (size_t)layer * 128 * TDIM, b + layer * 3 * EMB,
        hib, hob, layer < 2 ? 1 : 0);
    unsigned short* tb = hib; hib = hob; hob = tb;
  }
  // final h is in hib (h1_bf after 3 swaps)

  k_head<<<N_GRAPHS, 128, 0, stream>>>(hib, gs, fc1_w, fc1_b, fc2_w, fc2_b, out);
}

// Round 2
// 363.040 us; speedup vs baseline: 1.1981x; 1.1981x over previous
//
#include <hip/hip_runtime.h>

#define N_NODES 50000
#define N_EDGES 600000
#define N_GRAPHS 2048
#define EMB 128
#define TDIM 384
#define TS_LD 392               // padded LDS row stride (shorts): 2-way bank alias only
#define HN (N_NODES * EMB)
#define SCAN_NB ((N_NODES + 255) / 256)   // 196

// merged-prepass block ranges (384 threads/block)
#define PRE_ATOM_NB 8334        // 6 nodes/block, FULL wave (64 lanes x float2) per node
#define PRE_HIST_NB 1563        // ceil(600000/384)
#define PRE_WCONV_NB 384        // one (layer,col) per block
#define PRE_GB_NB 131           // ceil(50000/384)

typedef __attribute__((ext_vector_type(8))) short bf16x8;
typedef __attribute__((ext_vector_type(4))) float f32x4;
#define MFMA_BF16(a, b, c) __builtin_amdgcn_mfma_f32_16x16x32_bf16(a, b, c, 0, 0, 0)

__device__ inline unsigned short f2bf(float f) {
  unsigned int u = __float_as_uint(f);
  u += 0x7fffu + ((u >> 16) & 1u);   // round to nearest even
  return (unsigned short)(u >> 16);
}
__device__ inline float bf2f(unsigned short b) {
  return __uint_as_float(((unsigned int)b) << 16);
}
__device__ inline bf16x8 pack8(float4 lo, float4 hi) {
  bf16x8 r;
  r[0] = (short)f2bf(lo.x); r[1] = (short)f2bf(lo.y);
  r[2] = (short)f2bf(lo.z); r[3] = (short)f2bf(lo.w);
  r[4] = (short)f2bf(hi.x); r[5] = (short)f2bf(hi.y);
  r[6] = (short)f2bf(hi.z); r[7] = (short)f2bf(hi.w);
  return r;
}

// ---------------- merged prepass: atom-encoder | degree-hist | W-transpose | graph-bounds ----------
// Atom part: FULL wave per node. n is wave-uniform -> x-row reads are scalar loads.
// All 9 gathers are issued into an explicit v[9] array BEFORE any accumulation,
// forcing 9 loads in flight (round-0 kernel: VGPR_Count=16 proved the compiler
// serialized them into a 9-deep latency chain -> 44 us at 11% HBM).
__global__ __launch_bounds__(384) void k_pre(const int* __restrict__ x,
                                             const float* __restrict__ atom_emb,
                                             unsigned short* __restrict__ h_bf,
                                             const int* __restrict__ ei,
                                             int* __restrict__ deg,
                                             const float* __restrict__ W,
                                             unsigned short* __restrict__ wt,
                                             const int* __restrict__ batch,
                                             int* __restrict__ gs) {
  int blk = blockIdx.x;
  if (blk < PRE_ATOM_NB) {
    int n = blk * 6 + (threadIdx.x >> 6);
    int lane = threadIdx.x & 63;    // covers cols lane*2, lane*2+1
    if (n < N_NODES) {
      const int nu = __builtin_amdgcn_readfirstlane(n);
      const int* xr = x + nu * 9;
      int ix[9];
#pragma unroll
      for (int c = 0; c < 9; ++c) ix[c] = xr[c];            // scalar loads, issued together
      float2 v[9];
#pragma unroll
      for (int c = 0; c < 9; ++c)                           // 9 gathers, all in flight
        v[c] = ((const float2*)(atom_emb + (size_t)(c * 100 + ix[c]) * EMB))[lane];
      float2 acc = {0.f, 0.f};
#pragma unroll
      for (int c = 0; c < 9; ++c) { acc.x += v[c].x; acc.y += v[c].y; }
      *(ushort2*)(h_bf + (size_t)nu * EMB + lane * 2) = ushort2{f2bf(acc.x), f2bf(acc.y)};
    }
    return;
  }
  blk -= PRE_ATOM_NB;
  if (blk < PRE_HIST_NB) {
    int e = blk * 384 + threadIdx.x;
    if (e < N_EDGES) atomicAdd(&deg[ei[N_EDGES + e]], 1);
    return;
  }
  blk -= PRE_HIST_NB;
  if (blk < PRE_WCONV_NB) {
    int layer = blk >> 7, c = blk & 127, k = threadIdx.x;
    float v = W[(((layer * 3 + (k >> 7)) * 128) + (k & 127)) * 128 + c];
    wt[(size_t)blk * 384 + k] = f2bf(v);
    return;
  }
  blk -= PRE_WCONV_NB;
  {
    int i = blk * 384 + threadIdx.x;
    if (i < N_NODES) {
      int b = batch[i];
      int bp = (i == 0) ? -1 : batch[i - 1];
      for (int g = bp + 1; g <= b; ++g) gs[g] = i;
      if (i == N_NODES - 1) {
        for (int g = b + 1; g <= N_GRAPHS; ++g) gs[g] = N_NODES;
      }
    }
  }
}

// ---------------- CSR scan ----------------
__global__ __launch_bounds__(256) void k_scan_a(const int* __restrict__ deg,
                                                int* __restrict__ row_start,
                                                int* __restrict__ partials) {
  __shared__ int s[256];
  const int tid = threadIdx.x;
  const int i = blockIdx.x * 256 + tid;
  int v = (i < N_NODES) ? deg[i] : 0;
  s[tid] = v;
  __syncthreads();
  for (int off = 1; off < 256; off <<= 1) {
    int t = (tid >= off) ? s[tid - off] : 0;
    __syncthreads();
    s[tid] += t;
    __syncthreads();
  }
  if (i < N_NODES) row_start[i] = s[tid] - v;
  if (tid == 255) partials[blockIdx.x] = s[255];
}

__global__ __launch_bounds__(256) void k_scan_b(int* __restrict__ partials,
                                                int* __restrict__ row_start) {
  __shared__ int s[256];
  const int tid = threadIdx.x;
  int v = (tid < SCAN_NB) ? partials[tid] : 0;
  s[tid] = v;
  __syncthreads();
  for (int off = 1; off < 256; off <<= 1) {
    int t = (tid >= off) ? s[tid - off] : 0;
    __syncthreads();
    s[tid] += t;
    __syncthreads();
  }
  if (tid < SCAN_NB) partials[tid] = s[tid] - v;
  if (tid == 255) row_start[N_NODES] = s[255];
}

__global__ __launch_bounds__(256) void k_scan_c(int* __restrict__ row_start,
                                                const int* __restrict__ partials,
                                                int* __restrict__ cursor) {
  const int i = blockIdx.x * 256 + threadIdx.x;
  if (i < N_NODES) {
    int r = row_start[i] + partials[blockIdx.x];
    row_start[i] = r;
    cursor[i] = r;
  }
}

// Scatter edges into CSR order: one int2{src, packed_attr} per edge.
__global__ __launch_bounds__(256) void k_scatter(const int* __restrict__ ei,
                                                 const int* __restrict__ ea,
                                                 int* __restrict__ cursor,
                                                 int2* __restrict__ sorted_se) {
  int e = blockIdx.x * 256 + threadIdx.x;
  if (e >= N_EDGES) return;
  int src = ei[e], dst = ei[N_EDGES + e];
  int pos = atomicAdd(&cursor[dst], 1);
  int eap = ea[e * 3 + 0] | (ea[e * 3 + 1] << 3) | (ea[e * 3 + 2] << 6);
  sorted_se[pos] = int2{src, eap};
}

// ---------------- Edge aggregation: QUARTER-WAVE per node ----------------
// 16 lanes x bf16x8 = full 256B row per gather instruction. One wave covers 4 nodes
// x 8-edge unroll = 4 KB of gathers in flight (2x the old half-wave scheme) -- this
// phase is latency-bound (round-1 fused counters: 855 GB/s, 10.7% HBM), so MLP is
// the lever. 16 nodes/block (256 thr), grid 3125.
// Full 8-chunks run an UNCHECKED fast path; only the final partial chunk pays
// bounds logic. Accumulation order per column is unchanged vs round 0.
__global__ __launch_bounds__(256) void k_agg(const int2* __restrict__ sorted_se,
                                             const int* __restrict__ row_start,
                                             const float* __restrict__ bl,  // bond_emb[layer]: [3][8][3]
                                             const unsigned short* __restrict__ h_bf,
                                             unsigned short* __restrict__ t_bf) {
  __shared__ float4 combo[512];  // 8 KB
  for (int c = threadIdx.x; c < 512; c += 256) {
    int a0 = c & 7, a1 = (c >> 3) & 7, a2 = (c >> 6) & 7;
    combo[c] = float4{bl[a0 * 3 + 0] + bl[24 + a1 * 3 + 0] + bl[48 + a2 * 3 + 0],
                      bl[a0 * 3 + 1] + bl[24 + a1 * 3 + 1] + bl[48 + a2 * 3 + 1],
                      bl[a0 * 3 + 2] + bl[24 + a1 * 3 + 2] + bl[48 + a2 * 3 + 2], 0.f};
  }
  __syncthreads();
  const int node = blockIdx.x * 16 + (threadIdx.x >> 4);  // quarter-wave per node
  const int sub = threadIdx.x & 15;                       // cols sub*8..+7
  const int beg = row_start[node], end = row_start[node + 1];
  float4 l0 = {0.f, 0.f, 0.f, 0.f}, h0 = l0;   // channel 0: cols lo/hi
  float4 l1 = l0, h1 = l0;                     // channel 1
  float4 l2 = l0, h2 = l0;                     // channel 2
  int e = beg;
  const int full_end = beg + ((end - beg) & ~7);
  for (; e < full_end; e += 8) {           // fast path: no bounds logic
    int2 se[8];
#pragma unroll
    for (int j = 0; j < 8; ++j) se[j] = sorted_se[e + j];
    bf16x8 u[8];
#pragma unroll
    for (int j = 0; j < 8; ++j)
      u[j] = *(const bf16x8*)(h_bf + (size_t)se[j].x * EMB + sub * 8);
#pragma unroll
    for (int j = 0; j < 8; ++j) {
      float4 w = combo[se[j].y];
      float4 vlo = {bf2f((unsigned short)u[j][0]), bf2f((unsigned short)u[j][1]),
                    bf2f((unsigned short)u[j][2]), bf2f((unsigned short)u[j][3])};
      float4 vhi = {bf2f((unsigned short)u[j][4]), bf2f((unsigned short)u[j][5]),
                    bf2f((unsigned short)u[j][6]), bf2f((unsigned short)u[j][7])};
      l0 += vlo * w.x; h0 += vhi * w.x;
      l1 += vlo * w.y; h1 += vhi * w.y;
      l2 += vlo * w.z; h2 += vhi * w.z;
    }
  }
  if (e < end) {                           // tail chunk: clamped + weight-selected
    int2 se[8];
#pragma unroll
    for (int j = 0; j < 8; ++j) {
      int idx = e + j;
      se[j] = sorted_se[idx < end ? idx : end - 1];
    }
    bf16x8 u[8];
#pragma unroll
    for (int j = 0; j < 8; ++j)
      u[j] = *(const bf16x8*)(h_bf + (size_t)se[j].x * EMB + sub * 8);
#pragma unroll
    for (int j = 0; j < 8; ++j) {
      float4 w = (e + j < end) ? combo[se[j].y] : float4{0.f, 0.f, 0.f, 0.f};
      float4 vlo = {bf2f((unsigned short)u[j][0]), bf2f((unsigned short)u[j][1]),
                    bf2f((unsigned short)u[j][2]), bf2f((unsigned short)u[j][3])};
      float4 vhi = {bf2f((unsigned short)u[j][4]), bf2f((unsigned short)u[j][5]),
                    bf2f((unsigned short)u[j][6]), bf2f((unsigned short)u[j][7])};
      l0 += vlo * w.x; h0 += vhi * w.x;
      l1 += vlo * w.y; h1 += vhi * w.y;
      l2 += vlo * w.z; h2 += vhi * w.z;
    }
  }
  size_t base = (size_t)node * TDIM + sub * 8;
  *(bf16x8*)(t_bf + base)       = pack8(l0, h0);
  *(bf16x8*)(t_bf + base + 128) = pack8(l1, h1);
  *(bf16x8*)(t_bf + base + 256) = pack8(l2, h2);
}

// ---------------- MFMA GEMM: stage 32 t-rows into LDS, per-wave GEMM, bf16 residual ----------------
// Block 512 thr = 8 waves; 32 nodes/block; grid 1563. Wave wv owns cols wv*16..+15:
// 12 resident B-frags, 2 row-tiles (A via ds_read_b128), 12 chained MFMAs each.
// Epilogue: bias+relu + bf16 residual. h ping-pong (gather safety).
// A-frag: A[m=lane&15][k=(lane>>4)*8+j]; B-frag: B[k][n=lane&15];
// C/D: col=lane&15, row=(lane>>4)*4+reg.
__global__ __launch_bounds__(512) void k_gemm(const unsigned short* __restrict__ t_bf,
                                              const unsigned short* __restrict__ wt,  // [128][384]
                                              const float* __restrict__ bl,  // [3][128]
                                              const unsigned short* __restrict__ h_in_bf,
                                              unsigned short* __restrict__ h_out_bf,
                                              int do_relu) {
  __shared__ unsigned short ts[32 * TS_LD];   // 24.5 KB
  const int nb = blockIdx.x * 32;
  for (int i = threadIdx.x; i < 32 * 48; i += 512) {
    int r = i / 48, cc = i % 48;
    bf16x8 v = {};
    int row = nb + r;
    if (row < N_NODES) v = *(const bf16x8*)(t_bf + (size_t)row * TDIM + cc * 8);
    *(bf16x8*)(ts + r * TS_LD + cc * 8) = v;
  }
  __syncthreads();

  const int wv = threadIdx.x >> 6;
  const int lane = threadIdx.x & 63;
  const int m = lane & 15;
  const int kq = lane >> 4;
  const int c = wv * 16 + m;

  const unsigned short* pB = wt + (size_t)c * TDIM + kq * 8;
  bf16x8 B[12];
#pragma unroll
  for (int kc = 0; kc < 12; ++kc) B[kc] = *(const bf16x8*)(pB + kc * 32);

  const float bias = bl[c] + bl[128 + c] + bl[256 + c];

#pragma unroll
  for (int rt = 0; rt < 2; ++rt) {
    const unsigned short* pA = ts + (rt * 16 + m) * TS_LD + kq * 8;
    bf16x8 A[12];
#pragma unroll
    for (int kc = 0; kc < 12; ++kc) A[kc] = *(const bf16x8*)(pA + kc * 32);
    f32x4 acc = {0.f, 0.f, 0.f, 0.f};
#pragma unroll
    for (int kc = 0; kc < 12; ++kc) acc = MFMA_BF16(A[kc], B[kc], acc);
#pragma unroll
    for (int r = 0; r < 4; ++r) {
      int row = nb + rt * 16 + kq * 4 + r;
      if (row < N_NODES) {
        size_t idx = (size_t)row * EMB + c;
        float v = acc[r] + bias;
        if (do_relu) v = fmaxf(v, 0.f);
        float hn = bf2f(h_in_bf[idx]) + v;
        h_out_bf[idx] = f2bf(hn);
      }
    }
  }
}

// ---------------- fused mean-pool + head: block g reduces its contiguous node range ----------------
__global__ __launch_bounds__(128) void k_head(const unsigned short* __restrict__ h_bf,
                                              const int* __restrict__ gs,
                                              const float* __restrict__ fc1_w,
                                              const float* __restrict__ fc1_b,
                                              const float* __restrict__ fc2_w,
                                              const float* __restrict__ fc2_b,
                                              float* __restrict__ out) {
  __shared__ float hg[EMB];
  __shared__ float red[EMB];
  int g = blockIdx.x, e = threadIdx.x;
  int ns = gs[g], ne = gs[g + 1];
  float acc = 0.f;
  for (int n = ns; n < ne; ++n) acc += bf2f(h_bf[(size_t)n * EMB + e]);
  float cnt = fmaxf((float)(ne - ns), 1.f);
  hg[e] = acc / cnt;
  __syncthreads();
  float a2 = fc1_b[e];
  for (int j = 0; j < EMB; ++j) a2 += hg[j] * fc1_w[j * EMB + e];
  red[e] = a2 * fc2_w[e];
  __syncthreads();
  for (int s = 64; s > 0; s >>= 1) {
    if (e < s) red[e] += red[e + s];
    __syncthreads();
  }
  if (e == 0) out[g] = red[0] + fc2_b[0];
}

extern "C" void kernel_launch(void* const* d_in, const int* in_sizes, int n_in,
                              void* d_out, int out_size, void* d_ws, size_t ws_size,
                              hipStream_t stream) {
  const int*   x        = (const int*)d_in[0];
  const int*   ei       = (const int*)d_in[1];
  const int*   ea       = (const int*)d_in[2];
  const int*   batch    = (const int*)d_in[3];
  const float* atom_emb = (const float*)d_in[4];
  const float* bond_emb = (const float*)d_in[5];
  const float* W        = (const float*)d_in[6];
  const float* b        = (const float*)d_in[7];
  const float* fc1_w    = (const float*)d_in[8];
  const float* fc1_b    = (const float*)d_in[9];
  const float* fc2_w    = (const float*)d_in[10];
  const float* fc2_b    = (const float*)d_in[11];
  float* out = (float*)d_out;

  char* p = (char*)d_ws;
  auto alloc = [&](size_t bytes) { char* r = p; p += (bytes + 255) & ~(size_t)255; return r; };
  unsigned short* h0_bf      = (unsigned short*)alloc((size_t)HN * 2);
  unsigned short* h1_bf      = (unsigned short*)alloc((size_t)HN * 2);
  unsigned short* t_bf       = (unsigned short*)alloc((size_t)N_NODES * TDIM * 2);
  unsigned short* wt         = (unsigned short*)alloc((size_t)3 * 128 * TDIM * 2);
  int*            gs         = (int*)alloc((size_t)(N_GRAPHS + 1) * 4);
  int*            deg        = (int*)alloc((size_t)N_NODES * 4);
  int*            row_start  = (int*)alloc((size_t)(N_NODES + 1) * 4);
  int*            cursor     = (int*)alloc((size_t)N_NODES * 4);
  int*            partials   = (int*)alloc(256 * 4);
  int2*           sorted_se  = (int2*)alloc((size_t)(N_EDGES + 8) * 8);

  hipMemsetAsync(deg, 0, N_NODES * sizeof(int), stream);
  const int pre_blocks = PRE_ATOM_NB + PRE_HIST_NB + PRE_WCONV_NB + PRE_GB_NB;
  k_pre<<<pre_blocks, 384, 0, stream>>>(x, atom_emb, h0_bf, ei, deg, W, wt, batch, gs);
  k_scan_a<<<SCAN_NB, 256, 0, stream>>>(deg, row_start, partials);
  k_scan_b<<<1, 256, 0, stream>>>(partials, row_start);
  k_scan_c<<<SCAN_NB, 256, 0, stream>>>(row_start, partials, cursor);
  k_scatter<<<(N_EDGES + 255) / 256, 256, 0, stream>>>(ei, ea, cursor, sorted_se);

  unsigned short* hib = h0_bf;
  unsigned short* hob = h1_bf;
  const int gemm_blocks = (N_NODES + 31) / 32;  // 1563
  for (int layer = 0; layer < 3; ++layer) {
    k_agg<<<N_NODES / 16, 256, 0, stream>>>(sorted_se, row_start, bond_emb + layer * 72,
                                            hib, t_bf);
    k_gemm<<<gemm_blocks, 512, 0, stream>>>(
        t_bf, wt + (size_t)layer * 128 * TDIM, b + layer * 3 * EMB,
        hib, hob, layer < 2 ? 1 : 0);
    unsigned short* tb = hib; hib = hob; hob = tb;
  }
  // final h is in hib (h1_bf after 3 swaps)

  k_head<<<N_GRAPHS, 128, 0, stream>>>(hib, gs, fc1_w, fc1_b, fc2_w, fc2_b, out);
}

// Round 3
// 360.790 us; speedup vs baseline: 1.2056x; 1.0062x over previous
//
#include <hip/hip_runtime.h>

#define N_NODES 50000
#define N_EDGES 600000
#define N_GRAPHS 2048
#define EMB 128
#define TDIM 384
#define TS_LD 392               // padded LDS row stride (shorts): 2-way bank alias only
#define HN (N_NODES * EMB)
#define SCAN_NB ((N_NODES + 255) / 256)   // 196

// merged-prepass block ranges (384 threads/block)
#define PRE_ATOM_NB 8334        // 6 nodes/block, FULL wave per node (async LDS gathers)
#define PRE_HIST_NB 1563        // ceil(600000/384)
#define PRE_WCONV_NB 384        // one (layer,col) per block
#define PRE_GB_NB 131           // ceil(50000/384)

typedef __attribute__((ext_vector_type(8))) short bf16x8;
typedef __attribute__((ext_vector_type(4))) float f32x4;
#define MFMA_BF16(a, b, c) __builtin_amdgcn_mfma_f32_16x16x32_bf16(a, b, c, 0, 0, 0)

#define AS1 __attribute__((address_space(1)))
#define AS3 __attribute__((address_space(3)))
__device__ inline void gl_lds16(const void* g, void* l) {
  // async global->LDS, 16B/lane: LDS dest = l + lane*16 (wave-uniform base), no dest VGPRs
  __builtin_amdgcn_global_load_lds((const AS1 void*)g, (AS3 void*)l, 16, 0, 0);
}

__device__ inline unsigned short f2bf(float f) {
  unsigned int u = __float_as_uint(f);
  u += 0x7fffu + ((u >> 16) & 1u);   // round to nearest even
  return (unsigned short)(u >> 16);
}
__device__ inline float bf2f(unsigned short b) {
  return __uint_as_float(((unsigned int)b) << 16);
}
__device__ inline bf16x8 pack8(float4 lo, float4 hi) {
  bf16x8 r;
  r[0] = (short)f2bf(lo.x); r[1] = (short)f2bf(lo.y);
  r[2] = (short)f2bf(lo.z); r[3] = (short)f2bf(lo.w);
  r[4] = (short)f2bf(hi.x); r[5] = (short)f2bf(hi.y);
  r[6] = (short)f2bf(hi.z); r[7] = (short)f2bf(hi.w);
  return r;
}

// ---------------- merged prepass: atom-encoder | degree-hist | W-transpose | graph-bounds ----------
// Atom: one wave per node. Round-2 counters proved the VGPR-based gather loop stays a
// 9-deep serialized latency chain (VGPR_Count=16, 43.7us, 11% HBM) regardless of source
// order -- the register allocator sinks the loads. Fix: global_load_lds (width 16).
// Async direct-to-LDS loads have NO dest VGPR, so the scheduler cannot serialize them:
// 5 instructions cover all 9 embedding rows (lanes 0-31 -> row 2j, lanes 32-63 -> row
// 2j+1), one vmcnt(0), then LDS readback + sum. Same column pairs, same c=0..8 add
// order -> bitwise identical to before.
__global__ __launch_bounds__(384) void k_pre(const int* __restrict__ x,
                                             const float* __restrict__ atom_emb,
                                             unsigned short* __restrict__ h_bf,
                                             const int* __restrict__ ei,
                                             int* __restrict__ deg,
                                             const float* __restrict__ W,
                                             unsigned short* __restrict__ wt,
                                             const int* __restrict__ batch,
                                             int* __restrict__ gs) {
  // 6 waves x 5 KB: rows r=0..7 at wbase + r*128 floats; row 8 at wbase + 1024
  // (its lanes 32-63 write the 1152..1279 scratch tail, ignored)
  __shared__ float sb[6 * 1280];   // 30 KB
  int blk = blockIdx.x;
  if (blk < PRE_ATOM_NB) {
    const int wv = threadIdx.x >> 6;
    const int lane = threadIdx.x & 63;
    int n = blk * 6 + wv;
    if (n < N_NODES) {
      const int nu = __builtin_amdgcn_readfirstlane(n);
      const int* xr = x + nu * 9;
      int ix[9];
#pragma unroll
      for (int c = 0; c < 9; ++c) ix[c] = xr[c];   // wave-uniform -> s_loads
      float* wbase = sb + wv * 1280;
      const int half = lane >> 5;       // 0: lanes 0-31, 1: lanes 32-63
      const int sub16 = lane & 31;      // 16B slot within the row
#pragma unroll
      for (int j = 0; j < 4; ++j) {
        int c = 2 * j + half;
        const float* g = atom_emb + (size_t)(c * 100 + ix[c]) * EMB + sub16 * 4;
        gl_lds16(g, wbase + j * 256);   // row 2j -> +j*1024B, row 2j+1 -> +j*1024B+512B
      }
      {  // row 8: both halves load the same 512B (lanes 32-63 land in scratch tail)
        const float* g = atom_emb + (size_t)(8 * 100 + ix[8]) * EMB + sub16 * 4;
        gl_lds16(g, wbase + 1024);
      }
      asm volatile("s_waitcnt vmcnt(0)" ::: "memory");
      float2 acc = {0.f, 0.f};
#pragma unroll
      for (int c = 0; c < 9; ++c) {     // row c at wbase + c*128 floats
        float2 v = *(const float2*)(wbase + c * 128 + lane * 2);
        acc.x += v.x; acc.y += v.y;
      }
      *(ushort2*)(h_bf + (size_t)nu * EMB + lane * 2) = ushort2{f2bf(acc.x), f2bf(acc.y)};
    }
    return;
  }
  blk -= PRE_ATOM_NB;
  if (blk < PRE_HIST_NB) {
    int e = blk * 384 + threadIdx.x;
    if (e < N_EDGES) atomicAdd(&deg[ei[N_EDGES + e]], 1);
    return;
  }
  blk -= PRE_HIST_NB;
  if (blk < PRE_WCONV_NB) {
    int layer = blk >> 7, c = blk & 127, k = threadIdx.x;
    float v = W[(((layer * 3 + (k >> 7)) * 128) + (k & 127)) * 128 + c];
    wt[(size_t)blk * 384 + k] = f2bf(v);
    return;
  }
  blk -= PRE_WCONV_NB;
  {
    int i = blk * 384 + threadIdx.x;
    if (i < N_NODES) {
      int b = batch[i];
      int bp = (i == 0) ? -1 : batch[i - 1];
      for (int g = bp + 1; g <= b; ++g) gs[g] = i;
      if (i == N_NODES - 1) {
        for (int g = b + 1; g <= N_GRAPHS; ++g) gs[g] = N_NODES;
      }
    }
  }
}

// ---------------- CSR scan ----------------
__global__ __launch_bounds__(256) void k_scan_a(const int* __restrict__ deg,
                                                int* __restrict__ row_start,
                                                int* __restrict__ partials) {
  __shared__ int s[256];
  const int tid = threadIdx.x;
  const int i = blockIdx.x * 256 + tid;
  int v = (i < N_NODES) ? deg[i] : 0;
  s[tid] = v;
  __syncthreads();
  for (int off = 1; off < 256; off <<= 1) {
    int t = (tid >= off) ? s[tid - off] : 0;
    __syncthreads();
    s[tid] += t;
    __syncthreads();
  }
  if (i < N_NODES) row_start[i] = s[tid] - v;
  if (tid == 255) partials[blockIdx.x] = s[255];
}

__global__ __launch_bounds__(256) void k_scan_b(int* __restrict__ partials,
                                                int* __restrict__ row_start) {
  __shared__ int s[256];
  const int tid = threadIdx.x;
  int v = (tid < SCAN_NB) ? partials[tid] : 0;
  s[tid] = v;
  __syncthreads();
  for (int off = 1; off < 256; off <<= 1) {
    int t = (tid >= off) ? s[tid - off] : 0;
    __syncthreads();
    s[tid] += t;
    __syncthreads();
  }
  if (tid < SCAN_NB) partials[tid] = s[tid] - v;
  if (tid == 255) row_start[N_NODES] = s[255];
}

__global__ __launch_bounds__(256) void k_scan_c(int* __restrict__ row_start,
                                                const int* __restrict__ partials,
                                                int* __restrict__ cursor) {
  const int i = blockIdx.x * 256 + threadIdx.x;
  if (i < N_NODES) {
    int r = row_start[i] + partials[blockIdx.x];
    row_start[i] = r;
    cursor[i] = r;
  }
}

// Scatter edges into CSR order: one int2{src, packed_attr} per edge.
__global__ __launch_bounds__(256) void k_scatter(const int* __restrict__ ei,
                                                 const int* __restrict__ ea,
                                                 int* __restrict__ cursor,
                                                 int2* __restrict__ sorted_se) {
  int e = blockIdx.x * 256 + threadIdx.x;
  if (e >= N_EDGES) return;
  int src = ei[e], dst = ei[N_EDGES + e];
  int pos = atomicAdd(&cursor[dst], 1);
  int eap = ea[e * 3 + 0] | (ea[e * 3 + 1] << 3) | (ea[e * 3 + 2] << 6);
  sorted_se[pos] = int2{src, eap};
}

// ---------------- Edge aggregation: QUARTER-WAVE per node ----------------
// 16 lanes x bf16x8 = full 256B row per gather instruction. One wave covers 4 nodes
// x 8-edge unroll = 4 KB of gathers in flight. 16 nodes/block (256 thr), grid 3125.
__global__ __launch_bounds__(256) void k_agg(const int2* __restrict__ sorted_se,
                                             const int* __restrict__ row_start,
                                             const float* __restrict__ bl,  // bond_emb[layer]: [3][8][3]
                                             const unsigned short* __restrict__ h_bf,
                                             unsigned short* __restrict__ t_bf) {
  __shared__ float4 combo[512];  // 8 KB
  for (int c = threadIdx.x; c < 512; c += 256) {
    int a0 = c & 7, a1 = (c >> 3) & 7, a2 = (c >> 6) & 7;
    combo[c] = float4{bl[a0 * 3 + 0] + bl[24 + a1 * 3 + 0] + bl[48 + a2 * 3 + 0],
                      bl[a0 * 3 + 1] + bl[24 + a1 * 3 + 1] + bl[48 + a2 * 3 + 1],
                      bl[a0 * 3 + 2] + bl[24 + a1 * 3 + 2] + bl[48 + a2 * 3 + 2], 0.f};
  }
  __syncthreads();
  const int node = blockIdx.x * 16 + (threadIdx.x >> 4);  // quarter-wave per node
  const int sub = threadIdx.x & 15;                       // cols sub*8..+7
  const int beg = row_start[node], end = row_start[node + 1];
  float4 l0 = {0.f, 0.f, 0.f, 0.f}, h0 = l0;   // channel 0: cols lo/hi
  float4 l1 = l0, h1 = l0;                     // channel 1
  float4 l2 = l0, h2 = l0;                     // channel 2
  int e = beg;
  const int full_end = beg + ((end - beg) & ~7);
  for (; e < full_end; e += 8) {           // fast path: no bounds logic
    int2 se[8];
#pragma unroll
    for (int j = 0; j < 8; ++j) se[j] = sorted_se[e + j];
    bf16x8 u[8];
#pragma unroll
    for (int j = 0; j < 8; ++j)
      u[j] = *(const bf16x8*)(h_bf + (size_t)se[j].x * EMB + sub * 8);
#pragma unroll
    for (int j = 0; j < 8; ++j) {
      float4 w = combo[se[j].y];
      float4 vlo = {bf2f((unsigned short)u[j][0]), bf2f((unsigned short)u[j][1]),
                    bf2f((unsigned short)u[j][2]), bf2f((unsigned short)u[j][3])};
      float4 vhi = {bf2f((unsigned short)u[j][4]), bf2f((unsigned short)u[j][5]),
                    bf2f((unsigned short)u[j][6]), bf2f((unsigned short)u[j][7])};
      l0 += vlo * w.x; h0 += vhi * w.x;
      l1 += vlo * w.y; h1 += vhi * w.y;
      l2 += vlo * w.z; h2 += vhi * w.z;
    }
  }
  if (e < end) {                           // tail chunk: clamped + weight-selected
    int2 se[8];
#pragma unroll
    for (int j = 0; j < 8; ++j) {
      int idx = e + j;
      se[j] = sorted_se[idx < end ? idx : end - 1];
    }
    bf16x8 u[8];
#pragma unroll
    for (int j = 0; j < 8; ++j)
      u[j] = *(const bf16x8*)(h_bf + (size_t)se[j].x * EMB + sub * 8);
#pragma unroll
    for (int j = 0; j < 8; ++j) {
      float4 w = (e + j < end) ? combo[se[j].y] : float4{0.f, 0.f, 0.f, 0.f};
      float4 vlo = {bf2f((unsigned short)u[j][0]), bf2f((unsigned short)u[j][1]),
                    bf2f((unsigned short)u[j][2]), bf2f((unsigned short)u[j][3])};
      float4 vhi = {bf2f((unsigned short)u[j][4]), bf2f((unsigned short)u[j][5]),
                    bf2f((unsigned short)u[j][6]), bf2f((unsigned short)u[j][7])};
      l0 += vlo * w.x; h0 += vhi * w.x;
      l1 += vlo * w.y; h1 += vhi * w.y;
      l2 += vlo * w.z; h2 += vhi * w.z;
    }
  }
  size_t base = (size_t)node * TDIM + sub * 8;
  *(bf16x8*)(t_bf + base)       = pack8(l0, h0);
  *(bf16x8*)(t_bf + base + 128) = pack8(l1, h1);
  *(bf16x8*)(t_bf + base + 256) = pack8(l2, h2);
}

// ---------------- MFMA GEMM: stage 32 t-rows into LDS, per-wave GEMM, bf16 residual ----------------
// Block 512 thr = 8 waves; 32 nodes/block; grid 1563. Wave wv owns cols wv*16..+15:
// 12 resident B-frags, 2 row-tiles (A via ds_read_b128), 12 chained MFMAs each.
// A-frag: A[m=lane&15][k=(lane>>4)*8+j]; B-frag: B[k][n=lane&15];
// C/D: col=lane&15, row=(lane>>4)*4+reg.
__global__ __launch_bounds__(512) void k_gemm(const unsigned short* __restrict__ t_bf,
                                              const unsigned short* __restrict__ wt,  // [128][384]
                                              const float* __restrict__ bl,  // [3][128]
                                              const unsigned short* __restrict__ h_in_bf,
                                              unsigned short* __restrict__ h_out_bf,
                                              int do_relu) {
  __shared__ unsigned short ts[32 * TS_LD];   // 24.5 KB
  const int nb = blockIdx.x * 32;
  for (int i = threadIdx.x; i < 32 * 48; i += 512) {
    int r = i / 48, cc = i % 48;
    bf16x8 v = {};
    int row = nb + r;
    if (row < N_NODES) v = *(const bf16x8*)(t_bf + (size_t)row * TDIM + cc * 8);
    *(bf16x8*)(ts + r * TS_LD + cc * 8) = v;
  }
  __syncthreads();

  const int wv = threadIdx.x >> 6;
  const int lane = threadIdx.x & 63;
  const int m = lane & 15;
  const int kq = lane >> 4;
  const int c = wv * 16 + m;

  const unsigned short* pB = wt + (size_t)c * TDIM + kq * 8;
  bf16x8 B[12];
#pragma unroll
  for (int kc = 0; kc < 12; ++kc) B[kc] = *(const bf16x8*)(pB + kc * 32);

  const float bias = bl[c] + bl[128 + c] + bl[256 + c];

#pragma unroll
  for (int rt = 0; rt < 2; ++rt) {
    const unsigned short* pA = ts + (rt * 16 + m) * TS_LD + kq * 8;
    bf16x8 A[12];
#pragma unroll
    for (int kc = 0; kc < 12; ++kc) A[kc] = *(const bf16x8*)(pA + kc * 32);
    f32x4 acc = {0.f, 0.f, 0.f, 0.f};
#pragma unroll
    for (int kc = 0; kc < 12; ++kc) acc = MFMA_BF16(A[kc], B[kc], acc);
#pragma unroll
    for (int r = 0; r < 4; ++r) {
      int row = nb + rt * 16 + kq * 4 + r;
      if (row < N_NODES) {
        size_t idx = (size_t)row * EMB + c;
        float v = acc[r] + bias;
        if (do_relu) v = fmaxf(v, 0.f);
        float hn = bf2f(h_in_bf[idx]) + v;
        h_out_bf[idx] = f2bf(hn);
      }
    }
  }
}

// ---------------- fused mean-pool + head: block g reduces its contiguous node range ----------------
__global__ __launch_bounds__(128) void k_head(const unsigned short* __restrict__ h_bf,
                                              const int* __restrict__ gs,
                                              const float* __restrict__ fc1_w,
                                              const float* __restrict__ fc1_b,
                                              const float* __restrict__ fc2_w,
                                              const float* __restrict__ fc2_b,
                                              float* __restrict__ out) {
  __shared__ float hg[EMB];
  __shared__ float red[EMB];
  int g = blockIdx.x, e = threadIdx.x;
  int ns = gs[g], ne = gs[g + 1];
  float acc = 0.f;
  for (int n = ns; n < ne; ++n) acc += bf2f(h_bf[(size_t)n * EMB + e]);
  float cnt = fmaxf((float)(ne - ns), 1.f);
  hg[e] = acc / cnt;
  __syncthreads();
  float a2 = fc1_b[e];
  for (int j = 0; j < EMB; ++j) a2 += hg[j] * fc1_w[j * EMB + e];
  red[e] = a2 * fc2_w[e];
  __syncthreads();
  for (int s = 64; s > 0; s >>= 1) {
    if (e < s) red[e] += red[e + s];
    __syncthreads();
  }
  if (e == 0) out[g] = red[0] + fc2_b[0];
}

extern "C" void kernel_launch(void* const* d_in, const int* in_sizes, int n_in,
                              void* d_out, int out_size, void* d_ws, size_t ws_size,
                              hipStream_t stream) {
  const int*   x        = (const int*)d_in[0];
  const int*   ei       = (const int*)d_in[1];
  const int*   ea       = (const int*)d_in[2];
  const int*   batch    = (const int*)d_in[3];
  const float* atom_emb = (const float*)d_in[4];
  const float* bond_emb = (const float*)d_in[5];
  const float* W        = (const float*)d_in[6];
  const float* b        = (const float*)d_in[7];
  const float* fc1_w    = (const float*)d_in[8];
  const float* fc1_b    = (const float*)d_in[9];
  const float* fc2_w    = (const float*)d_in[10];
  const float* fc2_b    = (const float*)d_in[11];
  float* out = (float*)d_out;

  char* p = (char*)d_ws;
  auto alloc = [&](size_t bytes) { char* r = p; p += (bytes + 255) & ~(size_t)255; return r; };
  unsigned short* h0_bf      = (unsigned short*)alloc((size_t)HN * 2);
  unsigned short* h1_bf      = (unsigned short*)alloc((size_t)HN * 2);
  unsigned short* t_bf       = (unsigned short*)alloc((size_t)N_NODES * TDIM * 2);
  unsigned short* wt         = (unsigned short*)alloc((size_t)3 * 128 * TDIM * 2);
  int*            gs         = (int*)alloc((size_t)(N_GRAPHS + 1) * 4);
  int*            deg        = (int*)alloc((size_t)N_NODES * 4);
  int*            row_start  = (int*)alloc((size_t)(N_NODES + 1) * 4);
  int*            cursor     = (int*)alloc((size_t)N_NODES * 4);
  int*            partials   = (int*)alloc(256 * 4);
  int2*           sorted_se  = (int2*)alloc((size_t)(N_EDGES + 8) * 8);

  hipMemsetAsync(deg, 0, N_NODES * sizeof(int), stream);
  const int pre_blocks = PRE_ATOM_NB + PRE_HIST_NB + PRE_WCONV_NB + PRE_GB_NB;
  k_pre<<<pre_blocks, 384, 0, stream>>>(x, atom_emb, h0_bf, ei, deg, W, wt, batch, gs);
  k_scan_a<<<SCAN_NB, 256, 0, stream>>>(deg, row_start, partials);
  k_scan_b<<<1, 256, 0, stream>>>(partials, row_start);
  k_scan_c<<<SCAN_NB, 256, 0, stream>>>(row_start, partials, cursor);
  k_scatter<<<(N_EDGES + 255) / 256, 256, 0, stream>>>(ei, ea, cursor, sorted_se);

  unsigned short* hib = h0_bf;
  unsigned short* hob = h1_bf;
  const int gemm_blocks = (N_NODES + 31) / 32;  // 1563
  for (int layer = 0; layer < 3; ++layer) {
    k_agg<<<N_NODES / 16, 256, 0, stream>>>(sorted_se, row_start, bond_emb + layer * 72,
                                            hib, t_bf);
    k_gemm<<<gemm_blocks, 512, 0, stream>>>(
        t_bf, wt + (size_t)layer * 128 * TDIM, b + layer * 3 * EMB,
        hib, hob, layer < 2 ? 1 : 0);
    unsigned short* tb = hib; hib = hob; hob = tb;
  }
  // final h is in hib (h1_bf after 3 swaps)

  k_head<<<N_GRAPHS, 128, 0, stream>>>(hib, gs, fc1_w, fc1_b, fc2_w, fc2_b, out);
}

// Round 4
// 348.302 us; speedup vs baseline: 1.2488x; 1.0359x over previous
//
#include <hip/hip_runtime.h>

#define N_NODES 50000
#define N_EDGES 600000
#define N_GRAPHS 2048
#define EMB 128
#define TDIM 384
#define TS_LD 392               // padded LDS row stride (shorts): 2-way bank alias only
#define HN (N_NODES * EMB)
#define SCAN_NB ((N_NODES + 255) / 256)   // 196

// merged-prepass block ranges (384 threads/block)
#define PRE_ATOM_NB 8334        // 6 nodes/block, FULL wave per node (async LDS gathers)
#define PRE_HIST_NB 1563        // ceil(600000/384)
#define PRE_WCONV_NB 384        // one (layer,col) per block
#define PRE_GB_NB 131           // ceil(50000/384)

typedef __attribute__((ext_vector_type(8))) short bf16x8;
typedef __attribute__((ext_vector_type(4))) float f32x4;
#define MFMA_BF16(a, b, c) __builtin_amdgcn_mfma_f32_16x16x32_bf16(a, b, c, 0, 0, 0)

#define AS1 __attribute__((address_space(1)))
#define AS3 __attribute__((address_space(3)))
__device__ inline void gl_lds16(const void* g, void* l) {
  // async global->LDS, 16B/lane: LDS dest = l + lane*16 (wave-uniform base), no dest VGPRs
  __builtin_amdgcn_global_load_lds((const AS1 void*)g, (AS3 void*)l, 16, 0, 0);
}

__device__ inline unsigned short f2bf(float f) {
  unsigned int u = __float_as_uint(f);
  u += 0x7fffu + ((u >> 16) & 1u);   // round to nearest even
  return (unsigned short)(u >> 16);
}
__device__ inline float bf2f(unsigned short b) {
  return __uint_as_float(((unsigned int)b) << 16);
}
__device__ inline bf16x8 pack8(float4 lo, float4 hi) {
  bf16x8 r;
  r[0] = (short)f2bf(lo.x); r[1] = (short)f2bf(lo.y);
  r[2] = (short)f2bf(lo.z); r[3] = (short)f2bf(lo.w);
  r[4] = (short)f2bf(hi.x); r[5] = (short)f2bf(hi.y);
  r[6] = (short)f2bf(hi.z); r[7] = (short)f2bf(hi.w);
  return r;
}

// ---------------- merged prepass: atom-encoder | degree-hist+rank | W-transpose | graph-bounds -----
// Atom: async global_load_lds gathers (round-3: proved atom phase is NOT k_pre's critical
// path -- 43us invariant across 3 implementations). Hist: 600K device atomics ARE the
// suspected limiter (memory-side RMW, 192 atomics/line). This round: 4x replicated deg
// (contention /4) and the atomic's return value stored as the edge's rank -> k_scatter
// needs NO atomics at all.
__global__ __launch_bounds__(384) void k_pre(const int* __restrict__ x,
                                             const float* __restrict__ atom_emb,
                                             unsigned short* __restrict__ h_bf,
                                             const int* __restrict__ ei,
                                             int* __restrict__ deg4,   // [4][N_NODES]
                                             int* __restrict__ rank,   // [N_EDGES]
                                             const float* __restrict__ W,
                                             unsigned short* __restrict__ wt,
                                             const int* __restrict__ batch,
                                             int* __restrict__ gs) {
  __shared__ float sb[6 * 1280];   // 30 KB: 6 waves x (9 rows of 128f + scratch tail)
  int blk = blockIdx.x;
  if (blk < PRE_ATOM_NB) {
    const int wv = threadIdx.x >> 6;
    const int lane = threadIdx.x & 63;
    int n = blk * 6 + wv;
    if (n < N_NODES) {
      const int nu = __builtin_amdgcn_readfirstlane(n);
      const int* xr = x + nu * 9;
      int ix[9];
#pragma unroll
      for (int c = 0; c < 9; ++c) ix[c] = xr[c];   // wave-uniform -> s_loads
      float* wbase = sb + wv * 1280;
      const int half = lane >> 5;       // 0: lanes 0-31, 1: lanes 32-63
      const int sub16 = lane & 31;      // 16B slot within the row
#pragma unroll
      for (int j = 0; j < 4; ++j) {
        int c = 2 * j + half;
        const float* g = atom_emb + (size_t)(c * 100 + ix[c]) * EMB + sub16 * 4;
        gl_lds16(g, wbase + j * 256);   // row 2j -> +j*1024B, row 2j+1 -> +j*1024B+512B
      }
      {  // row 8: both halves load the same 512B (lanes 32-63 land in scratch tail)
        const float* g = atom_emb + (size_t)(8 * 100 + ix[8]) * EMB + sub16 * 4;
        gl_lds16(g, wbase + 1024);
      }
      asm volatile("s_waitcnt vmcnt(0)" ::: "memory");
      float2 acc = {0.f, 0.f};
#pragma unroll
      for (int c = 0; c < 9; ++c) {     // row c at wbase + c*128 floats
        float2 v = *(const float2*)(wbase + c * 128 + lane * 2);
        acc.x += v.x; acc.y += v.y;
      }
      *(ushort2*)(h_bf + (size_t)nu * EMB + lane * 2) = ushort2{f2bf(acc.x), f2bf(acc.y)};
    }
    return;
  }
  blk -= PRE_ATOM_NB;
  if (blk < PRE_HIST_NB) {
    int e = blk * 384 + threadIdx.x;
    if (e < N_EDGES) {
      int d = ei[N_EDGES + e];
      int r = blk & 3;                               // replica, recomputable as (e/384)&3
      rank[e] = atomicAdd(&deg4[r * N_NODES + d], 1);  // rank within (replica, node)
    }
    return;
  }
  blk -= PRE_HIST_NB;
  if (blk < PRE_WCONV_NB) {
    int layer = blk >> 7, c = blk & 127, k = threadIdx.x;
    float v = W[(((layer * 3 + (k >> 7)) * 128) + (k & 127)) * 128 + c];
    wt[(size_t)blk * 384 + k] = f2bf(v);
    return;
  }
  blk -= PRE_WCONV_NB;
  {
    int i = blk * 384 + threadIdx.x;
    if (i < N_NODES) {
      int b = batch[i];
      int bp = (i == 0) ? -1 : batch[i - 1];
      for (int g = bp + 1; g <= b; ++g) gs[g] = i;
      if (i == N_NODES - 1) {
        for (int g = b + 1; g <= N_GRAPHS; ++g) gs[g] = N_NODES;
      }
    }
  }
}

// ---------------- CSR scan (sums 4 deg replicas; packs per-replica byte offsets) ----------------
__global__ __launch_bounds__(256) void k_scan_a(const int* __restrict__ deg4,
                                                int* __restrict__ row_start,
                                                int* __restrict__ partials,
                                                int* __restrict__ base4) {
  __shared__ int s[256];
  const int tid = threadIdx.x;
  const int i = blockIdx.x * 256 + tid;
  int v = 0;
  if (i < N_NODES) {
    int d0 = deg4[i];
    int d1 = deg4[N_NODES + i];
    int d2 = deg4[2 * N_NODES + i];
    int d3 = deg4[3 * N_NODES + i];
    v = d0 + d1 + d2 + d3;
    // exclusive per-replica offsets within the node's CSR range (deg << 255 -> byte-safe)
    base4[i] = (d0 << 8) | ((d0 + d1) << 16) | ((unsigned)(d0 + d1 + d2) << 24);
  }
  s[tid] = v;
  __syncthreads();
  for (int off = 1; off < 256; off <<= 1) {
    int t = (tid >= off) ? s[tid - off] : 0;
    __syncthreads();
    s[tid] += t;
    __syncthreads();
  }
  if (i < N_NODES) row_start[i] = s[tid] - v;
  if (tid == 255) partials[blockIdx.x] = s[255];
}

__global__ __launch_bounds__(256) void k_scan_b(int* __restrict__ partials,
                                                int* __restrict__ row_start) {
  __shared__ int s[256];
  const int tid = threadIdx.x;
  int v = (tid < SCAN_NB) ? partials[tid] : 0;
  s[tid] = v;
  __syncthreads();
  for (int off = 1; off < 256; off <<= 1) {
    int t = (tid >= off) ? s[tid - off] : 0;
    __syncthreads();
    s[tid] += t;
    __syncthreads();
  }
  if (tid < SCAN_NB) partials[tid] = s[tid] - v;
  if (tid == 255) row_start[N_NODES] = s[255];
}

__global__ __launch_bounds__(256) void k_scan_c(int* __restrict__ row_start,
                                                const int* __restrict__ partials) {
  const int i = blockIdx.x * 256 + threadIdx.x;
  if (i < N_NODES) row_start[i] += partials[blockIdx.x];
}

// Scatter edges into CSR order -- ATOMIC-FREE: pos = row_start + packed replica base + rank.
__global__ __launch_bounds__(256) void k_scatter(const int* __restrict__ ei,
                                                 const int* __restrict__ ea,
                                                 const int* __restrict__ rank,
                                                 const int* __restrict__ row_start,
                                                 const int* __restrict__ base4,
                                                 int2* __restrict__ sorted_se) {
  int e = blockIdx.x * 256 + threadIdx.x;
  if (e >= N_EDGES) return;
  int src = ei[e], dst = ei[N_EDGES + e];
  int r = (e / 384) & 3;                        // same replica mapping as k_pre hist
  int base = (base4[dst] >> (r * 8)) & 255;     // r==0 -> low byte == 0
  int pos = row_start[dst] + base + rank[e];
  int eap = ea[e * 3 + 0] | (ea[e * 3 + 1] << 3) | (ea[e * 3 + 2] << 6);
  sorted_se[pos] = int2{src, eap};
}

// ---------------- Edge aggregation: QUARTER-WAVE per node ----------------
// 16 lanes x bf16x8 = full 256B row per gather instruction. One wave covers 4 nodes
// x 8-edge unroll = 4 KB of gathers in flight. 16 nodes/block (256 thr), grid 3125.
__global__ __launch_bounds__(256) void k_agg(const int2* __restrict__ sorted_se,
                                             const int* __restrict__ row_start,
                                             const float* __restrict__ bl,  // bond_emb[layer]: [3][8][3]
                                             const unsigned short* __restrict__ h_bf,
                                             unsigned short* __restrict__ t_bf) {
  __shared__ float4 combo[512];  // 8 KB
  for (int c = threadIdx.x; c < 512; c += 256) {
    int a0 = c & 7, a1 = (c >> 3) & 7, a2 = (c >> 6) & 7;
    combo[c] = float4{bl[a0 * 3 + 0] + bl[24 + a1 * 3 + 0] + bl[48 + a2 * 3 + 0],
                      bl[a0 * 3 + 1] + bl[24 + a1 * 3 + 1] + bl[48 + a2 * 3 + 1],
                      bl[a0 * 3 + 2] + bl[24 + a1 * 3 + 2] + bl[48 + a2 * 3 + 2], 0.f};
  }
  __syncthreads();
  const int node = blockIdx.x * 16 + (threadIdx.x >> 4);  // quarter-wave per node
  const int sub = threadIdx.x & 15;                       // cols sub*8..+7
  const int beg = row_start[node], end = row_start[node + 1];
  float4 l0 = {0.f, 0.f, 0.f, 0.f}, h0 = l0;   // channel 0: cols lo/hi
  float4 l1 = l0, h1 = l0;                     // channel 1
  float4 l2 = l0, h2 = l0;                     // channel 2
  int e = beg;
  const int full_end = beg + ((end - beg) & ~7);
  for (; e < full_end; e += 8) {           // fast path: no bounds logic
    int2 se[8];
#pragma unroll
    for (int j = 0; j < 8; ++j) se[j] = sorted_se[e + j];
    bf16x8 u[8];
#pragma unroll
    for (int j = 0; j < 8; ++j)
      u[j] = *(const bf16x8*)(h_bf + (size_t)se[j].x * EMB + sub * 8);
#pragma unroll
    for (int j = 0; j < 8; ++j) {
      float4 w = combo[se[j].y];
      float4 vlo = {bf2f((unsigned short)u[j][0]), bf2f((unsigned short)u[j][1]),
                    bf2f((unsigned short)u[j][2]), bf2f((unsigned short)u[j][3])};
      float4 vhi = {bf2f((unsigned short)u[j][4]), bf2f((unsigned short)u[j][5]),
                    bf2f((unsigned short)u[j][6]), bf2f((unsigned short)u[j][7])};
      l0 += vlo * w.x; h0 += vhi * w.x;
      l1 += vlo * w.y; h1 += vhi * w.y;
      l2 += vlo * w.z; h2 += vhi * w.z;
    }
  }
  if (e < end) {                           // tail chunk: clamped + weight-selected
    int2 se[8];
#pragma unroll
    for (int j = 0; j < 8; ++j) {
      int idx = e + j;
      se[j] = sorted_se[idx < end ? idx : end - 1];
    }
    bf16x8 u[8];
#pragma unroll
    for (int j = 0; j < 8; ++j)
      u[j] = *(const bf16x8*)(h_bf + (size_t)se[j].x * EMB + sub * 8);
#pragma unroll
    for (int j = 0; j < 8; ++j) {
      float4 w = (e + j < end) ? combo[se[j].y] : float4{0.f, 0.f, 0.f, 0.f};
      float4 vlo = {bf2f((unsigned short)u[j][0]), bf2f((unsigned short)u[j][1]),
                    bf2f((unsigned short)u[j][2]), bf2f((unsigned short)u[j][3])};
      float4 vhi = {bf2f((unsigned short)u[j][4]), bf2f((unsigned short)u[j][5]),
                    bf2f((unsigned short)u[j][6]), bf2f((unsigned short)u[j][7])};
      l0 += vlo * w.x; h0 += vhi * w.x;
      l1 += vlo * w.y; h1 += vhi * w.y;
      l2 += vlo * w.z; h2 += vhi * w.z;
    }
  }
  size_t base = (size_t)node * TDIM + sub * 8;
  *(bf16x8*)(t_bf + base)       = pack8(l0, h0);
  *(bf16x8*)(t_bf + base + 128) = pack8(l1, h1);
  *(bf16x8*)(t_bf + base + 256) = pack8(l2, h2);
}

// ---------------- MFMA GEMM: stage 32 t-rows into LDS, per-wave GEMM, bf16 residual ----------------
// Block 512 thr = 8 waves; 32 nodes/block; grid 1563. Wave wv owns cols wv*16..+15:
// 12 resident B-frags, 2 row-tiles (A via ds_read_b128), 12 chained MFMAs each.
// A-frag: A[m=lane&15][k=(lane>>4)*8+j]; B-frag: B[k][n=lane&15];
// C/D: col=lane&15, row=(lane>>4)*4+reg.
__global__ __launch_bounds__(512) void k_gemm(const unsigned short* __restrict__ t_bf,
                                              const unsigned short* __restrict__ wt,  // [128][384]
                                              const float* __restrict__ bl,  // [3][128]
                                              const unsigned short* __restrict__ h_in_bf,
                                              unsigned short* __restrict__ h_out_bf,
                                              int do_relu) {
  __shared__ unsigned short ts[32 * TS_LD];   // 24.5 KB
  const int nb = blockIdx.x * 32;
  for (int i = threadIdx.x; i < 32 * 48; i += 512) {
    int r = i / 48, cc = i % 48;
    bf16x8 v = {};
    int row = nb + r;
    if (row < N_NODES) v = *(const bf16x8*)(t_bf + (size_t)row * TDIM + cc * 8);
    *(bf16x8*)(ts + r * TS_LD + cc * 8) = v;
  }
  __syncthreads();

  const int wv = threadIdx.x >> 6;
  const int lane = threadIdx.x & 63;
  const int m = lane & 15;
  const int kq = lane >> 4;
  const int c = wv * 16 + m;

  const unsigned short* pB = wt + (size_t)c * TDIM + kq * 8;
  bf16x8 B[12];
#pragma unroll
  for (int kc = 0; kc < 12; ++kc) B[kc] = *(const bf16x8*)(pB + kc * 32);

  const float bias = bl[c] + bl[128 + c] + bl[256 + c];

#pragma unroll
  for (int rt = 0; rt < 2; ++rt) {
    const unsigned short* pA = ts + (rt * 16 + m) * TS_LD + kq * 8;
    bf16x8 A[12];
#pragma unroll
    for (int kc = 0; kc < 12; ++kc) A[kc] = *(const bf16x8*)(pA + kc * 32);
    f32x4 acc = {0.f, 0.f, 0.f, 0.f};
#pragma unroll
    for (int kc = 0; kc < 12; ++kc) acc = MFMA_BF16(A[kc], B[kc], acc);
#pragma unroll
    for (int r = 0; r < 4; ++r) {
      int row = nb + rt * 16 + kq * 4 + r;
      if (row < N_NODES) {
        size_t idx = (size_t)row * EMB + c;
        float v = acc[r] + bias;
        if (do_relu) v = fmaxf(v, 0.f);
        float hn = bf2f(h_in_bf[idx]) + v;
        h_out_bf[idx] = f2bf(hn);
      }
    }
  }
}

// ---------------- fused mean-pool + head: block g reduces its contiguous node range ----------------
__global__ __launch_bounds__(128) void k_head(const unsigned short* __restrict__ h_bf,
                                              const int* __restrict__ gs,
                                              const float* __restrict__ fc1_w,
                                              const float* __restrict__ fc1_b,
                                              const float* __restrict__ fc2_w,
                                              const float* __restrict__ fc2_b,
                                              float* __restrict__ out) {
  __shared__ float hg[EMB];
  __shared__ float red[EMB];
  int g = blockIdx.x, e = threadIdx.x;
  int ns = gs[g], ne = gs[g + 1];
  float acc = 0.f;
  for (int n = ns; n < ne; ++n) acc += bf2f(h_bf[(size_t)n * EMB + e]);
  float cnt = fmaxf((float)(ne - ns), 1.f);
  hg[e] = acc / cnt;
  __syncthreads();
  float a2 = fc1_b[e];
  for (int j = 0; j < EMB; ++j) a2 += hg[j] * fc1_w[j * EMB + e];
  red[e] = a2 * fc2_w[e];
  __syncthreads();
  for (int s = 64; s > 0; s >>= 1) {
    if (e < s) red[e] += red[e + s];
    __syncthreads();
  }
  if (e == 0) out[g] = red[0] + fc2_b[0];
}

extern "C" void kernel_launch(void* const* d_in, const int* in_sizes, int n_in,
                              void* d_out, int out_size, void* d_ws, size_t ws_size,
                              hipStream_t stream) {
  const int*   x        = (const int*)d_in[0];
  const int*   ei       = (const int*)d_in[1];
  const int*   ea       = (const int*)d_in[2];
  const int*   batch    = (const int*)d_in[3];
  const float* atom_emb = (const float*)d_in[4];
  const float* bond_emb = (const float*)d_in[5];
  const float* W        = (const float*)d_in[6];
  const float* b        = (const float*)d_in[7];
  const float* fc1_w    = (const float*)d_in[8];
  const float* fc1_b    = (const float*)d_in[9];
  const float* fc2_w    = (const float*)d_in[10];
  const float* fc2_b    = (const float*)d_in[11];
  float* out = (float*)d_out;

  char* p = (char*)d_ws;
  auto alloc = [&](size_t bytes) { char* r = p; p += (bytes + 255) & ~(size_t)255; return r; };
  unsigned short* h0_bf      = (unsigned short*)alloc((size_t)HN * 2);
  unsigned short* h1_bf      = (unsigned short*)alloc((size_t)HN * 2);
  unsigned short* t_bf       = (unsigned short*)alloc((size_t)N_NODES * TDIM * 2);
  unsigned short* wt         = (unsigned short*)alloc((size_t)3 * 128 * TDIM * 2);
  int*            gs         = (int*)alloc((size_t)(N_GRAPHS + 1) * 4);
  int*            deg4       = (int*)alloc((size_t)4 * N_NODES * 4);
  int*            rank       = (int*)alloc((size_t)N_EDGES * 4);
  int*            base4      = (int*)alloc((size_t)N_NODES * 4);
  int*            row_start  = (int*)alloc((size_t)(N_NODES + 1) * 4);
  int*            partials   = (int*)alloc(256 * 4);
  int2*           sorted_se  = (int2*)alloc((size_t)(N_EDGES + 8) * 8);

  hipMemsetAsync(deg4, 0, 4 * N_NODES * sizeof(int), stream);
  const int pre_blocks = PRE_ATOM_NB + PRE_HIST_NB + PRE_WCONV_NB + PRE_GB_NB;
  k_pre<<<pre_blocks, 384, 0, stream>>>(x, atom_emb, h0_bf, ei, deg4, rank, W, wt, batch, gs);
  k_scan_a<<<SCAN_NB, 256, 0, stream>>>(deg4, row_start, partials, base4);
  k_scan_b<<<1, 256, 0, stream>>>(partials, row_start);
  k_scan_c<<<SCAN_NB, 256, 0, stream>>>(row_start, partials);
  k_scatter<<<(N_EDGES + 255) / 256, 256, 0, stream>>>(ei, ea, rank, row_start, base4, sorted_se);

  unsigned short* hib = h0_bf;
  unsigned short* hob = h1_bf;
  const int gemm_blocks = (N_NODES + 31) / 32;  // 1563
  for (int layer = 0; layer < 3; ++layer) {
    k_agg<<<N_NODES / 16, 256, 0, stream>>>(sorted_se, row_start, bond_emb + layer * 72,
                                            hib, t_bf);
    k_gemm<<<gemm_blocks, 512, 0, stream>>>(
        t_bf, wt + (size_t)layer * 128 * TDIM, b + layer * 3 * EMB,
        hib, hob, layer < 2 ? 1 : 0);
    unsigned short* tb = hib; hib = hob; hob = tb;
  }
  // final h is in hib (h1_bf after 3 swaps)

  k_head<<<N_GRAPHS, 128, 0, stream>>>(hib, gs, fc1_w, fc1_b, fc2_w, fc2_b, out);
}